// Round 13
// baseline (263.383 us; speedup 1.0000x reference)
//
#include <hip/hip_runtime.h>
#include <hip/hip_bf16.h>

#define N_NODES 50000
#define N_EDGES 800000
#define F 128
#define NC 41
#define SCAN_BLK 256
#define N_SCAN_BLKS ((N_NODES + SCAN_BLK - 1) / SCAN_BLK)   // 196
#define NSLICE 8
#define SLICE_NODES (N_NODES / NSLICE)   // 6250 exactly
#define FILL_BLKS_PER_SLICE 256

typedef __attribute__((ext_vector_type(4))) float f32x4;
typedef __attribute__((ext_vector_type(8))) short bf16x8;   // 8 bf16 = 4 VGPRs

__device__ __forceinline__ float bf2f(unsigned short u) {
    unsigned int x = ((unsigned int)u) << 16;
    return __uint_as_float(x);
}
__device__ __forceinline__ unsigned short f2bf(float f) {
    unsigned int x = __float_as_uint(f);
    unsigned int lsb = (x >> 16) & 1u;
    x += 0x7fffu + lsb;
    return (unsigned short)(x >> 16);
}

// XCD-sliced degree count: deg lines for a slice are touched by one XCD only.
__global__ __launch_bounds__(256) void count_deg_sliced_kernel(const int* __restrict__ dst,
                                                               int* __restrict__ deg) {
    int slice = blockIdx.x & (NSLICE - 1);
    int bid = blockIdx.x >> 3;
    int lo = slice * SLICE_NODES, hi = lo + SLICE_NODES;
    int stride = FILL_BLKS_PER_SLICE * 256;
    for (int e = bid * 256 + threadIdx.x; e < N_EDGES; e += stride) {
        int d = dst[e];
        if (d >= lo && d < hi) atomicAdd(&deg[d], 1);
    }
}

__global__ __launch_bounds__(SCAN_BLK) void scan1_kernel(const int* __restrict__ deg,
                                                         int* __restrict__ local,
                                                         int* __restrict__ bsum) {
    __shared__ int buf[SCAN_BLK];
    int tid = threadIdx.x;
    int i = blockIdx.x * SCAN_BLK + tid;
    int v = (i < N_NODES) ? deg[i] : 0;
    buf[tid] = v;
    __syncthreads();
#pragma unroll
    for (int off = 1; off < SCAN_BLK; off <<= 1) {
        int t = (tid >= off) ? buf[tid - off] : 0;
        __syncthreads();
        buf[tid] += t;
        __syncthreads();
    }
    if (i < N_NODES) local[i] = buf[tid] - v;
    if (tid == SCAN_BLK - 1) bsum[blockIdx.x] = buf[tid];
}

__global__ __launch_bounds__(SCAN_BLK) void scan2_kernel(int* __restrict__ bsum,
                                                         int* __restrict__ row_ptr) {
    __shared__ int buf[SCAN_BLK];
    int tid = threadIdx.x;
    int v = (tid < N_SCAN_BLKS) ? bsum[tid] : 0;
    buf[tid] = v;
    __syncthreads();
#pragma unroll
    for (int off = 1; off < SCAN_BLK; off <<= 1) {
        int t = (tid >= off) ? buf[tid - off] : 0;
        __syncthreads();
        buf[tid] += t;
        __syncthreads();
    }
    if (tid < N_SCAN_BLKS) bsum[tid] = buf[tid] - v;
    if (tid == SCAN_BLK - 1) row_ptr[N_NODES] = buf[tid];
}

__global__ __launch_bounds__(SCAN_BLK) void scan3_kernel(const int* __restrict__ deg,
                                                         const int* __restrict__ local,
                                                         const int* __restrict__ bsum,
                                                         int* __restrict__ row_ptr,
                                                         int* __restrict__ cursor,
                                                         float* __restrict__ inv_deg) {
    int i = blockIdx.x * SCAN_BLK + threadIdx.x;
    if (i < N_NODES) {
        int rp = local[i] + bsum[blockIdx.x];
        row_ptr[i] = rp;
        cursor[i] = rp;
        inv_deg[i] = 1.0f / fmaxf((float)deg[i], 1.0f);
    }
}

// XCD-sliced CSR fill: slice = blockIdx & 7 -> (round-robin dispatch) one XCD per slice.
__global__ __launch_bounds__(256) void fill_csr_sliced_kernel(const int* __restrict__ src,
                                                              const int* __restrict__ dst,
                                                              int* __restrict__ cursor,
                                                              int* __restrict__ csr_src) {
    int slice = blockIdx.x & (NSLICE - 1);
    int bid = blockIdx.x >> 3;
    int lo = slice * SLICE_NODES, hi = lo + SLICE_NODES;
    int stride = FILL_BLKS_PER_SLICE * 256;
    for (int e = bid * 256 + threadIdx.x; e < N_EDGES; e += stride) {
        int d = dst[e];
        if (d >= lo && d < hi) {
            int p = atomicAdd(&cursor[d], 1);
            csr_src[p] = src[e];
        }
    }
}

// Fused weight pack (both GEMMs), MFMA B-fragment order (bf16).
// Bpk[((ct*4+kb)*64+l)*8+j] = W[k][c], k=kb*32+(l>>4)*8+j, c=ct*16+(l&15).
// W0 logical [128][256] = [W_self0 | W_neigh0]; W1 logical [128][128]:
// cols 0..40 = W_self1, 64..104 = W_neigh1, else 0.
__global__ void pack_w_kernel(const float* __restrict__ Ws0, const float* __restrict__ Wn0,
                              const float* __restrict__ Ws1, const float* __restrict__ Wn1,
                              unsigned short* __restrict__ Bpk0,
                              unsigned short* __restrict__ Bpk1) {
    int i = blockIdx.x * blockDim.x + threadIdx.x;
    if (i < 128 * 256) {
        int j = i & 7, l = (i >> 3) & 63, kb = (i >> 9) & 3, ct = i >> 11;
        int k = kb * 32 + (l >> 4) * 8 + j;
        int c = ct * 16 + (l & 15);
        float v = (c < F) ? Ws0[k * F + c] : Wn0[k * F + (c - F)];
        Bpk0[i] = f2bf(v);
    } else if (i < 128 * 256 + 128 * 128) {
        int i2 = i - 128 * 256;
        int j = i2 & 7, l = (i2 >> 3) & 63, kb = (i2 >> 9) & 3, ct = i2 >> 11;
        int k = kb * 32 + (l >> 4) * 8 + j;
        int c = ct * 16 + (l & 15);
        float v = 0.0f;
        if (c < 48) { if (c < NC) v = Ws1[k * NC + c]; }
        else if (c >= 64 && c < 112) { int cc = c - 64; if (cc < NC) v = Wn1[k * NC + cc]; }
        Bpk1[i2] = f2bf(v);
    }
}

// MFMA GEMM: C[M][4*CT*16] = A[M][128] @ W. 64-row tile/block, 4 waves, wave covers CT*16 cols.
template<bool AF32, int CT, int MODE>
__global__ __launch_bounds__(256) void gemm_mfma_kernel(const void* __restrict__ Av,
                                                        const unsigned short* __restrict__ Bpk,
                                                        int M,
                                                        unsigned short* __restrict__ outA,
                                                        unsigned short* __restrict__ outB) {
    __shared__ unsigned short As[64 * 128];  // bf16, XOR-swizzled: idx ^= (row&7)<<3
    int tid = threadIdx.x;
    int wave = tid >> 6, lane = tid & 63;
    int row0 = blockIdx.x * 64;

    if (AF32) {
        const float* A = (const float*)Av;
#pragma unroll
        for (int i = 0; i < 8; ++i) {
            int fid = tid + i * 256;            // float4 id: 2048 total (64 rows x 32)
            int row = fid >> 5, c4 = (fid & 31) * 4;
            int grow = row0 + row; if (grow > M - 1) grow = M - 1;
            f32x4 v = *(const f32x4*)(A + (size_t)grow * F + c4);
            unsigned int p0 = (unsigned)f2bf(v.x) | ((unsigned)f2bf(v.y) << 16);
            unsigned int p1 = (unsigned)f2bf(v.z) | ((unsigned)f2bf(v.w) << 16);
            int idx = (row * 128 + c4) ^ ((row & 7) << 3);
            *(uint2*)&As[idx] = make_uint2(p0, p1);
        }
    } else {
        const unsigned short* A = (const unsigned short*)Av;
#pragma unroll
        for (int i = 0; i < 4; ++i) {
            int fid = tid + i * 256;            // uint4 id: 1024 total (64 rows x 16 chunks of 8 bf16)
            int row = fid >> 4, c8 = (fid & 15) * 8;
            int grow = row0 + row; if (grow > M - 1) grow = M - 1;
            uint4 v = *(const uint4*)&A[(size_t)grow * F + c8];
            int idx = (row * 128 + c8) ^ ((row & 7) << 3);
            *(uint4*)&As[idx] = v;
        }
    }
    __syncthreads();

    f32x4 acc[4][CT];
#pragma unroll
    for (int m = 0; m < 4; ++m)
#pragma unroll
        for (int n = 0; n < CT; ++n) acc[m][n] = (f32x4){0.f, 0.f, 0.f, 0.f};

#pragma unroll
    for (int kb = 0; kb < 4; ++kb) {
        bf16x8 afr[4];
#pragma unroll
        for (int m = 0; m < 4; ++m) {
            int row = m * 16 + (lane & 15);
            int ke = kb * 32 + (lane >> 4) * 8;
            int idx = (row * 128 + ke) ^ ((row & 7) << 3);
            afr[m] = *(const bf16x8*)&As[idx];
        }
#pragma unroll
        for (int n = 0; n < CT; ++n) {
            int ct = wave * CT + n;
            bf16x8 bfr = *(const bf16x8*)&Bpk[((ct * 4 + kb) * 64 + lane) * 8];
#pragma unroll
            for (int m = 0; m < 4; ++m)
                acc[m][n] = __builtin_amdgcn_mfma_f32_16x16x32_bf16(afr[m], bfr, acc[m][n], 0, 0, 0);
        }
    }

#pragma unroll
    for (int m = 0; m < 4; ++m) {
#pragma unroll
        for (int i = 0; i < 4; ++i) {
            int r = row0 + m * 16 + (lane >> 4) * 4 + i;
            if (r < M) {
#pragma unroll
                for (int n = 0; n < CT; ++n) {
                    int c = (wave * CT + n) * 16 + (lane & 15);
                    unsigned short val = f2bf(acc[m][n][i]);
                    if (MODE == 0) {
                        outA[(size_t)r * (CT * 64) + c] = val;
                    } else {
                        if (c < 48) outA[(size_t)r * 48 + c] = val;
                        else if (c >= 64 && c < 112) outB[(size_t)r * 48 + (c - 64)] = val;
                    }
                }
            }
        }
    }
}

// h[node] = relu(u_self + mean(u_neigh) + b0); u is bf16 [N][256] (self 0..127, neigh 128..255).
// 4 waves/block, wave = one node, lane t = 2 cols; edge loop unrolled x8 (8 gathers in flight).
__global__ __launch_bounds__(256) void agg0_kernel(const unsigned int* __restrict__ u,
                                                   const int* __restrict__ row_ptr,
                                                   const int* __restrict__ csr_src,
                                                   const float* __restrict__ inv_deg,
                                                   const float* __restrict__ b0,
                                                   unsigned int* __restrict__ hu) {
    int node = blockIdx.x * 4 + (threadIdx.x >> 6);
    int t = threadIdx.x & 63;
    int s = row_ptr[node], e = row_ptr[node + 1];
    float ax = 0.f, ay = 0.f, bx = 0.f, by = 0.f;
    int j = s;
    for (; j + 7 < e; j += 8) {
        int sr0 = csr_src[j],     sr1 = csr_src[j + 1];
        int sr2 = csr_src[j + 2], sr3 = csr_src[j + 3];
        int sr4 = csr_src[j + 4], sr5 = csr_src[j + 5];
        int sr6 = csr_src[j + 6], sr7 = csr_src[j + 7];
        unsigned int v0 = u[(size_t)sr0 * 128 + 64 + t];
        unsigned int v1 = u[(size_t)sr1 * 128 + 64 + t];
        unsigned int v2 = u[(size_t)sr2 * 128 + 64 + t];
        unsigned int v3 = u[(size_t)sr3 * 128 + 64 + t];
        unsigned int v4 = u[(size_t)sr4 * 128 + 64 + t];
        unsigned int v5 = u[(size_t)sr5 * 128 + 64 + t];
        unsigned int v6 = u[(size_t)sr6 * 128 + 64 + t];
        unsigned int v7 = u[(size_t)sr7 * 128 + 64 + t];
        ax += bf2f((unsigned short)(v0 & 0xffffu)) + bf2f((unsigned short)(v1 & 0xffffu));
        ay += bf2f((unsigned short)(v0 >> 16)) + bf2f((unsigned short)(v1 >> 16));
        bx += bf2f((unsigned short)(v2 & 0xffffu)) + bf2f((unsigned short)(v3 & 0xffffu));
        by += bf2f((unsigned short)(v2 >> 16)) + bf2f((unsigned short)(v3 >> 16));
        ax += bf2f((unsigned short)(v4 & 0xffffu)) + bf2f((unsigned short)(v5 & 0xffffu));
        ay += bf2f((unsigned short)(v4 >> 16)) + bf2f((unsigned short)(v5 >> 16));
        bx += bf2f((unsigned short)(v6 & 0xffffu)) + bf2f((unsigned short)(v7 & 0xffffu));
        by += bf2f((unsigned short)(v6 >> 16)) + bf2f((unsigned short)(v7 >> 16));
    }
    for (; j < e; ++j) {
        int sr = csr_src[j];
        unsigned int v = u[(size_t)sr * 128 + 64 + t];
        ax += bf2f((unsigned short)(v & 0xffffu));
        ay += bf2f((unsigned short)(v >> 16));
    }
    ax += bx; ay += by;
    float inv = inv_deg[node];
    unsigned int vs = u[(size_t)node * 128 + t];
    float2 bb = ((const float2*)b0)[t];
    float h0 = fmaxf(bf2f((unsigned short)(vs & 0xffffu)) + ax * inv + bb.x, 0.0f);
    float h1 = fmaxf(bf2f((unsigned short)(vs >> 16)) + ay * inv + bb.y, 0.0f);
    hu[(size_t)node * 64 + t] = (unsigned)f2bf(h0) | ((unsigned)f2bf(h1) << 16);
}

// out[node][c] = t_self[node][c] + b1[c] + mean(t_neigh[src][c]); t_* bf16 [N][48].
// 4 waves/block, wave = one node, two 32-lane groups on alternating edges, x8 unroll per group.
__global__ __launch_bounds__(256) void final_out_kernel(const unsigned int* __restrict__ ts,
                                                        const unsigned int* __restrict__ tn,
                                                        const int* __restrict__ row_ptr,
                                                        const int* __restrict__ csr_src,
                                                        const float* __restrict__ inv_deg,
                                                        const float* __restrict__ b1,
                                                        float* __restrict__ out) {
    int node = blockIdx.x * 4 + (threadIdx.x >> 6);
    int lane = threadIdx.x & 63;
    int group = lane >> 5;       // 0 or 1
    int c = lane & 31;           // col-pair index; active c<24 (stray loads land in pad)
    int s = row_ptr[node], e = row_ptr[node + 1];
    float ax = 0.f, ay = 0.f, bx = 0.f, by = 0.f;
    int j = s + group;
    for (; j + 14 < e; j += 16) {
        int sr0 = csr_src[j],      sr1 = csr_src[j + 2];
        int sr2 = csr_src[j + 4],  sr3 = csr_src[j + 6];
        int sr4 = csr_src[j + 8],  sr5 = csr_src[j + 10];
        int sr6 = csr_src[j + 12], sr7 = csr_src[j + 14];
        unsigned int v0 = tn[(size_t)sr0 * 24 + c];
        unsigned int v1 = tn[(size_t)sr1 * 24 + c];
        unsigned int v2 = tn[(size_t)sr2 * 24 + c];
        unsigned int v3 = tn[(size_t)sr3 * 24 + c];
        unsigned int v4 = tn[(size_t)sr4 * 24 + c];
        unsigned int v5 = tn[(size_t)sr5 * 24 + c];
        unsigned int v6 = tn[(size_t)sr6 * 24 + c];
        unsigned int v7 = tn[(size_t)sr7 * 24 + c];
        ax += bf2f((unsigned short)(v0 & 0xffffu)) + bf2f((unsigned short)(v1 & 0xffffu));
        ay += bf2f((unsigned short)(v0 >> 16)) + bf2f((unsigned short)(v1 >> 16));
        bx += bf2f((unsigned short)(v2 & 0xffffu)) + bf2f((unsigned short)(v3 & 0xffffu));
        by += bf2f((unsigned short)(v2 >> 16)) + bf2f((unsigned short)(v3 >> 16));
        ax += bf2f((unsigned short)(v4 & 0xffffu)) + bf2f((unsigned short)(v5 & 0xffffu));
        ay += bf2f((unsigned short)(v4 >> 16)) + bf2f((unsigned short)(v5 >> 16));
        bx += bf2f((unsigned short)(v6 & 0xffffu)) + bf2f((unsigned short)(v7 & 0xffffu));
        by += bf2f((unsigned short)(v6 >> 16)) + bf2f((unsigned short)(v7 >> 16));
    }
    for (; j < e; j += 2) {
        int sr = csr_src[j];
        unsigned int v = tn[(size_t)sr * 24 + c];
        ax += bf2f((unsigned short)(v & 0xffffu));
        ay += bf2f((unsigned short)(v >> 16));
    }
    ax += bx; ay += by;
    ax += __shfl(ax, lane + 32, 64);
    ay += __shfl(ay, lane + 32, 64);
    if (lane >= 24) return;
    float inv = inv_deg[node];
    unsigned int vs = ts[(size_t)node * 24 + c];
    int c0 = 2 * c, c1 = 2 * c + 1;
    if (c0 < NC)
        out[(size_t)node * NC + c0] = bf2f((unsigned short)(vs & 0xffffu)) + b1[c0] + ax * inv;
    if (c1 < NC)
        out[(size_t)node * NC + c1] = bf2f((unsigned short)(vs >> 16)) + b1[c1] + ay * inv;
}

extern "C" void kernel_launch(void* const* d_in, const int* in_sizes, int n_in,
                              void* d_out, int out_size, void* d_ws, size_t ws_size,
                              hipStream_t stream) {
    const float* x   = (const float*)d_in[0];
    const int*   src = (const int*)d_in[1];
    const int*   dst = (const int*)d_in[2];
    const float* Ws0 = (const float*)d_in[3];
    const float* Wn0 = (const float*)d_in[4];
    const float* b0  = (const float*)d_in[5];
    const float* Ws1 = (const float*)d_in[6];
    const float* Wn1 = (const float*)d_in[7];
    const float* b1  = (const float*)d_in[8];
    float* out = (float*)d_out;

    char* ws = (char*)d_ws;
    size_t o = 0;
    auto alloc = [&](size_t bytes) {
        size_t r = o;
        o = (o + bytes + 255) & ~(size_t)255;
        return r;
    };
    int*   deg     = (int*)(ws + alloc(sizeof(int) * N_NODES));
    int*   local   = (int*)(ws + alloc(sizeof(int) * N_NODES));
    int*   bsum    = (int*)(ws + alloc(sizeof(int) * N_SCAN_BLKS));
    int*   row_ptr = (int*)(ws + alloc(sizeof(int) * (N_NODES + 1)));
    int*   cursor  = (int*)(ws + alloc(sizeof(int) * N_NODES));
    int*   csr     = (int*)(ws + alloc(sizeof(int) * N_EDGES));
    float* inv_deg = (float*)(ws + alloc(sizeof(float) * N_NODES));
    unsigned short* Bpk0 = (unsigned short*)(ws + alloc(sizeof(short) * 128 * 256));
    unsigned short* Bpk1 = (unsigned short*)(ws + alloc(sizeof(short) * 128 * 128));
    unsigned short* u    = (unsigned short*)(ws + alloc(sizeof(short) * (size_t)N_NODES * 256));
    unsigned short* h    = (unsigned short*)(ws + alloc(sizeof(short) * (size_t)N_NODES * 128));
    unsigned short* t_self  = (unsigned short*)(ws + alloc(sizeof(short) * (size_t)N_NODES * 48));
    unsigned short* t_neigh = (unsigned short*)(ws + alloc(sizeof(short) * ((size_t)N_NODES * 48 + 128)));  // +pad for stray lane reads

    hipMemsetAsync(deg, 0, sizeof(int) * N_NODES, stream);
    count_deg_sliced_kernel<<<NSLICE * FILL_BLKS_PER_SLICE, 256, 0, stream>>>(dst, deg);
    scan1_kernel<<<N_SCAN_BLKS, SCAN_BLK, 0, stream>>>(deg, local, bsum);
    scan2_kernel<<<1, SCAN_BLK, 0, stream>>>(bsum, row_ptr);
    scan3_kernel<<<N_SCAN_BLKS, SCAN_BLK, 0, stream>>>(deg, local, bsum, row_ptr, cursor, inv_deg);
    fill_csr_sliced_kernel<<<NSLICE * FILL_BLKS_PER_SLICE, 256, 0, stream>>>(src, dst, cursor, csr);
    pack_w_kernel<<<(128 * 256 + 128 * 128 + 255) / 256, 256, 0, stream>>>(Ws0, Wn0, Ws1, Wn1,
                                                                           Bpk0, Bpk1);

    int nblk = (N_NODES + 63) / 64;  // 782
    // GEMM A: u = bf16(x) @ [Ws0|Wn0]  -> u bf16 [N][256]
    gemm_mfma_kernel<true, 4, 0><<<nblk, 256, 0, stream>>>(x, Bpk0, N_NODES, u, nullptr);
    // agg0: h = relu(u_self + mean(u_neigh) + b0) -> bf16 [N][128]
    agg0_kernel<<<N_NODES / 4, 256, 0, stream>>>((const unsigned int*)u, row_ptr, csr, inv_deg, b0,
                                                 (unsigned int*)h);
    // GEMM B: t = h @ Wcat1 -> t_self bf16[N][48], t_neigh bf16[N][48]
    gemm_mfma_kernel<false, 2, 1><<<nblk, 256, 0, stream>>>(h, Bpk1, N_NODES, t_self, t_neigh);
    // final: out = t_self + b1 + mean(t_neigh)
    final_out_kernel<<<N_NODES / 4, 256, 0, stream>>>((const unsigned int*)t_self,
                                                      (const unsigned int*)t_neigh,
                                                      row_ptr, csr, inv_deg, b1, out);
}

// Round 14
// 262.121 us; speedup vs baseline: 1.0048x; 1.0048x over previous
//
#include <hip/hip_runtime.h>
#include <hip/hip_bf16.h>

#define N_NODES 50000
#define N_EDGES 800000
#define F 128
#define NC 41
#define SCAN_BLK 256
#define N_SCAN_BLKS ((N_NODES + SCAN_BLK - 1) / SCAN_BLK)   // 196
#define NSLICE 8
#define SLICE_NODES (N_NODES / NSLICE)   // 6250 exactly
#define FILL_BLKS_PER_SLICE 256
#define FILL_BLKS (NSLICE * FILL_BLKS_PER_SLICE)            // 2048
#define COUNT_BLKS ((N_EDGES + 255) / 256)                  // 3125
#define PACK_BLKS ((128 * 256 + 128 * 128) / 256)           // 192
#define GEMM_BLKS ((N_NODES + 63) / 64)                     // 782

typedef __attribute__((ext_vector_type(4))) float f32x4;
typedef __attribute__((ext_vector_type(8))) short bf16x8;   // 8 bf16 = 4 VGPRs

__device__ __forceinline__ float bf2f(unsigned short u) {
    unsigned int x = ((unsigned int)u) << 16;
    return __uint_as_float(x);
}
__device__ __forceinline__ unsigned short f2bf(float f) {
    unsigned int x = __float_as_uint(f);
    unsigned int lsb = (x >> 16) & 1u;
    x += 0x7fffu + lsb;
    return (unsigned short)(x >> 16);
}
// fp8 e4m3fn codec (manual; subnormals flushed to 0 on encode, never produced on decode).
__device__ __forceinline__ float fp8dec(unsigned int b) {
    unsigned int t = ((b & 0x80u) << 24) | ((b & 0x7fu) << 20);
    return __uint_as_float(t) * 0x1.0p+120f;
}
__device__ __forceinline__ unsigned char fp8enc(float v) {
    unsigned int u = __float_as_uint(v);
    unsigned int s = (u >> 24) & 0x80u;
    float a = fabsf(v);
    if (a < 0.015625f) return (unsigned char)s;   // below min normal -> signed zero
    a = fminf(a, 448.0f);                         // e4m3fn max finite
    unsigned int b = __float_as_uint(a);
    b += 0x0007FFFFu + ((b >> 20) & 1u);          // RNE at 3-bit mantissa
    unsigned int E = (b >> 23) - 120u;            // in [1,15]
    unsigned int M = (b >> 20) & 7u;
    return (unsigned char)(s | (E << 3) | M);
}

// Fused: degree count (edge-parallel atomics) + weight pack (independent work).
// Bpk[((ct*4+kb)*64+l)*8+j] = W[k][c], k=kb*32+(l>>4)*8+j, c=ct*16+(l&15).
__global__ __launch_bounds__(256) void count_pack_kernel(const int* __restrict__ dst,
                                                         int* __restrict__ deg,
                                                         const float* __restrict__ Ws0,
                                                         const float* __restrict__ Wn0,
                                                         const float* __restrict__ Ws1,
                                                         const float* __restrict__ Wn1,
                                                         unsigned short* __restrict__ Bpk0,
                                                         unsigned short* __restrict__ Bpk1) {
    if (blockIdx.x < COUNT_BLKS) {
        int e = blockIdx.x * 256 + threadIdx.x;
        if (e < N_EDGES) atomicAdd(&deg[dst[e]], 1);
    } else {
        int i = (blockIdx.x - COUNT_BLKS) * 256 + threadIdx.x;
        if (i < 128 * 256) {
            int j = i & 7, l = (i >> 3) & 63, kb = (i >> 9) & 3, ct = i >> 11;
            int k = kb * 32 + (l >> 4) * 8 + j;
            int c = ct * 16 + (l & 15);
            float v = (c < F) ? Ws0[k * F + c] : Wn0[k * F + (c - F)];
            Bpk0[i] = f2bf(v);
        } else if (i < 128 * 256 + 128 * 128) {
            int i2 = i - 128 * 256;
            int j = i2 & 7, l = (i2 >> 3) & 63, kb = (i2 >> 9) & 3, ct = i2 >> 11;
            int k = kb * 32 + (l >> 4) * 8 + j;
            int c = ct * 16 + (l & 15);
            float v = 0.0f;
            if (c < 48) { if (c < NC) v = Ws1[k * NC + c]; }
            else if (c >= 64 && c < 112) { int cc = c - 64; if (cc < NC) v = Wn1[k * NC + cc]; }
            Bpk1[i2] = f2bf(v);
        }
    }
}

__global__ __launch_bounds__(SCAN_BLK) void scan1_kernel(const int* __restrict__ deg,
                                                         int* __restrict__ local,
                                                         int* __restrict__ bsum) {
    __shared__ int buf[SCAN_BLK];
    int tid = threadIdx.x;
    int i = blockIdx.x * SCAN_BLK + tid;
    int v = (i < N_NODES) ? deg[i] : 0;
    buf[tid] = v;
    __syncthreads();
#pragma unroll
    for (int off = 1; off < SCAN_BLK; off <<= 1) {
        int t = (tid >= off) ? buf[tid - off] : 0;
        __syncthreads();
        buf[tid] += t;
        __syncthreads();
    }
    if (i < N_NODES) local[i] = buf[tid] - v;
    if (tid == SCAN_BLK - 1) bsum[blockIdx.x] = buf[tid];
}

__global__ __launch_bounds__(SCAN_BLK) void scan2_kernel(int* __restrict__ bsum,
                                                         int* __restrict__ row_ptr) {
    __shared__ int buf[SCAN_BLK];
    int tid = threadIdx.x;
    int v = (tid < N_SCAN_BLKS) ? bsum[tid] : 0;
    buf[tid] = v;
    __syncthreads();
#pragma unroll
    for (int off = 1; off < SCAN_BLK; off <<= 1) {
        int t = (tid >= off) ? buf[tid - off] : 0;
        __syncthreads();
        buf[tid] += t;
        __syncthreads();
    }
    if (tid < N_SCAN_BLKS) bsum[tid] = buf[tid] - v;
    if (tid == SCAN_BLK - 1) row_ptr[N_NODES] = buf[tid];
}

__global__ __launch_bounds__(SCAN_BLK) void scan3_kernel(const int* __restrict__ deg,
                                                         const int* __restrict__ local,
                                                         const int* __restrict__ bsum,
                                                         int* __restrict__ row_ptr,
                                                         int* __restrict__ cursor,
                                                         float* __restrict__ inv_deg) {
    int i = blockIdx.x * SCAN_BLK + threadIdx.x;
    if (i < N_NODES) {
        int rp = local[i] + bsum[blockIdx.x];
        row_ptr[i] = rp;
        cursor[i] = rp;
        inv_deg[i] = 1.0f / fmaxf((float)deg[i], 1.0f);
    }
}

// Fused: XCD-sliced CSR fill (blocks 0..2047) + MFMA GEMM A (blocks 2048..2829).
// Independent work: fill writes csr/cursor from src/dst; gemm reads x/Bpk0, writes u.
// Fill's latency-bound atomics co-schedule with GEMM's MFMA on the same CUs.
// GEMM A: u_self bf16[N][128] = bf16(x)@Ws0 ; u_neigh fp8 e4m3[N][128] = bf16(x)@Wn0.
__global__ __launch_bounds__(256) void fill_gemmA_kernel(const int* __restrict__ src,
                                                         const int* __restrict__ dst,
                                                         int* __restrict__ cursor,
                                                         int* __restrict__ csr_src,
                                                         const float* __restrict__ x,
                                                         const unsigned short* __restrict__ Bpk,
                                                         unsigned short* __restrict__ u_self,
                                                         unsigned char* __restrict__ u_neigh8) {
    __shared__ unsigned short As[64 * 128];  // bf16, XOR-swizzled: idx ^= (row&7)<<3
    if (blockIdx.x < FILL_BLKS) {
        int slice = blockIdx.x & (NSLICE - 1);
        int bid = blockIdx.x >> 3;
        int lo = slice * SLICE_NODES, hi = lo + SLICE_NODES;
        int stride = FILL_BLKS_PER_SLICE * 256;
        for (int e = bid * 256 + threadIdx.x; e < N_EDGES; e += stride) {
            int d = dst[e];
            if (d >= lo && d < hi) {
                int p = atomicAdd(&cursor[d], 1);
                csr_src[p] = src[e];
            }
        }
        return;
    }
    int tid = threadIdx.x;
    int wave = tid >> 6, lane = tid & 63;
    int row0 = (blockIdx.x - FILL_BLKS) * 64;

#pragma unroll
    for (int i = 0; i < 8; ++i) {
        int fid = tid + i * 256;            // float4 id: 2048 total (64 rows x 32)
        int row = fid >> 5, c4 = (fid & 31) * 4;
        int grow = row0 + row; if (grow > N_NODES - 1) grow = N_NODES - 1;
        f32x4 v = *(const f32x4*)(x + (size_t)grow * F + c4);
        unsigned int p0 = (unsigned)f2bf(v.x) | ((unsigned)f2bf(v.y) << 16);
        unsigned int p1 = (unsigned)f2bf(v.z) | ((unsigned)f2bf(v.w) << 16);
        int idx = (row * 128 + c4) ^ ((row & 7) << 3);
        *(uint2*)&As[idx] = make_uint2(p0, p1);
    }
    __syncthreads();

    f32x4 acc[4][4];
#pragma unroll
    for (int m = 0; m < 4; ++m)
#pragma unroll
        for (int n = 0; n < 4; ++n) acc[m][n] = (f32x4){0.f, 0.f, 0.f, 0.f};

#pragma unroll
    for (int kb = 0; kb < 4; ++kb) {
        bf16x8 afr[4];
#pragma unroll
        for (int m = 0; m < 4; ++m) {
            int row = m * 16 + (lane & 15);
            int ke = kb * 32 + (lane >> 4) * 8;
            int idx = (row * 128 + ke) ^ ((row & 7) << 3);
            afr[m] = *(const bf16x8*)&As[idx];
        }
#pragma unroll
        for (int n = 0; n < 4; ++n) {
            int ct = wave * 4 + n;
            bf16x8 bfr = *(const bf16x8*)&Bpk[((ct * 4 + kb) * 64 + lane) * 8];
#pragma unroll
            for (int m = 0; m < 4; ++m)
                acc[m][n] = __builtin_amdgcn_mfma_f32_16x16x32_bf16(afr[m], bfr, acc[m][n], 0, 0, 0);
        }
    }

#pragma unroll
    for (int m = 0; m < 4; ++m) {
#pragma unroll
        for (int i = 0; i < 4; ++i) {
            int r = row0 + m * 16 + (lane >> 4) * 4 + i;
            if (r < N_NODES) {
#pragma unroll
                for (int n = 0; n < 4; ++n) {
                    int c = (wave * 4 + n) * 16 + (lane & 15);
                    float v = acc[m][n][i];
                    if (c < 128) u_self[(size_t)r * 128 + c] = f2bf(v);
                    else         u_neigh8[(size_t)r * 128 + (c - 128)] = fp8enc(v);
                }
            }
        }
    }
}

// GEMM B: t = h @ Wcat1. 64-row tile, 4 waves, CT=2. cols<48 -> t_self, 64<=c<112 -> t_neigh.
__global__ __launch_bounds__(256) void gemmB_kernel(const unsigned short* __restrict__ A,
                                                    const unsigned short* __restrict__ Bpk,
                                                    unsigned short* __restrict__ outA,
                                                    unsigned short* __restrict__ outB) {
    __shared__ unsigned short As[64 * 128];
    int tid = threadIdx.x;
    int wave = tid >> 6, lane = tid & 63;
    int row0 = blockIdx.x * 64;

#pragma unroll
    for (int i = 0; i < 4; ++i) {
        int fid = tid + i * 256;            // uint4 id: 1024 total (64 rows x 16 chunks of 8 bf16)
        int row = fid >> 4, c8 = (fid & 15) * 8;
        int grow = row0 + row; if (grow > N_NODES - 1) grow = N_NODES - 1;
        uint4 v = *(const uint4*)&A[(size_t)grow * F + c8];
        int idx = (row * 128 + c8) ^ ((row & 7) << 3);
        *(uint4*)&As[idx] = v;
    }
    __syncthreads();

    f32x4 acc[4][2];
#pragma unroll
    for (int m = 0; m < 4; ++m)
#pragma unroll
        for (int n = 0; n < 2; ++n) acc[m][n] = (f32x4){0.f, 0.f, 0.f, 0.f};

#pragma unroll
    for (int kb = 0; kb < 4; ++kb) {
        bf16x8 afr[4];
#pragma unroll
        for (int m = 0; m < 4; ++m) {
            int row = m * 16 + (lane & 15);
            int ke = kb * 32 + (lane >> 4) * 8;
            int idx = (row * 128 + ke) ^ ((row & 7) << 3);
            afr[m] = *(const bf16x8*)&As[idx];
        }
#pragma unroll
        for (int n = 0; n < 2; ++n) {
            int ct = wave * 2 + n;
            bf16x8 bfr = *(const bf16x8*)&Bpk[((ct * 4 + kb) * 64 + lane) * 8];
#pragma unroll
            for (int m = 0; m < 4; ++m)
                acc[m][n] = __builtin_amdgcn_mfma_f32_16x16x32_bf16(afr[m], bfr, acc[m][n], 0, 0, 0);
        }
    }

#pragma unroll
    for (int m = 0; m < 4; ++m) {
#pragma unroll
        for (int i = 0; i < 4; ++i) {
            int r = row0 + m * 16 + (lane >> 4) * 4 + i;
            if (r < N_NODES) {
#pragma unroll
                for (int n = 0; n < 2; ++n) {
                    int c = (wave * 2 + n) * 16 + (lane & 15);
                    unsigned short val = f2bf(acc[m][n][i]);
                    if (c < 48) outA[(size_t)r * 48 + c] = val;
                    else if (c >= 64 && c < 112) outB[(size_t)r * 48 + (c - 64)] = val;
                }
            }
        }
    }
}

// h[node] = relu(u_self + mean(u_neigh) + b0); u_self bf16 [N][128], u_neigh fp8 [N][128].
// 4 waves/block, wave = one node, lane t = 2 cols (2 fp8 bytes/edge); x8 edge unroll.
__global__ __launch_bounds__(256) void agg0_kernel(const unsigned int* __restrict__ us,
                                                   const unsigned short* __restrict__ un8,
                                                   const int* __restrict__ row_ptr,
                                                   const int* __restrict__ csr_src,
                                                   const float* __restrict__ inv_deg,
                                                   const float* __restrict__ b0,
                                                   unsigned int* __restrict__ hu) {
    int node = blockIdx.x * 4 + (threadIdx.x >> 6);
    int t = threadIdx.x & 63;
    int s = row_ptr[node], e = row_ptr[node + 1];
    float ax = 0.f, ay = 0.f, bx = 0.f, by = 0.f;
    int j = s;
    for (; j + 7 < e; j += 8) {
        int sr0 = csr_src[j],     sr1 = csr_src[j + 1];
        int sr2 = csr_src[j + 2], sr3 = csr_src[j + 3];
        int sr4 = csr_src[j + 4], sr5 = csr_src[j + 5];
        int sr6 = csr_src[j + 6], sr7 = csr_src[j + 7];
        unsigned int w0 = un8[(size_t)sr0 * 64 + t];
        unsigned int w1 = un8[(size_t)sr1 * 64 + t];
        unsigned int w2 = un8[(size_t)sr2 * 64 + t];
        unsigned int w3 = un8[(size_t)sr3 * 64 + t];
        unsigned int w4 = un8[(size_t)sr4 * 64 + t];
        unsigned int w5 = un8[(size_t)sr5 * 64 + t];
        unsigned int w6 = un8[(size_t)sr6 * 64 + t];
        unsigned int w7 = un8[(size_t)sr7 * 64 + t];
        ax += fp8dec(w0 & 0xffu) + fp8dec(w1 & 0xffu);
        ay += fp8dec(w0 >> 8)    + fp8dec(w1 >> 8);
        bx += fp8dec(w2 & 0xffu) + fp8dec(w3 & 0xffu);
        by += fp8dec(w2 >> 8)    + fp8dec(w3 >> 8);
        ax += fp8dec(w4 & 0xffu) + fp8dec(w5 & 0xffu);
        ay += fp8dec(w4 >> 8)    + fp8dec(w5 >> 8);
        bx += fp8dec(w6 & 0xffu) + fp8dec(w7 & 0xffu);
        by += fp8dec(w6 >> 8)    + fp8dec(w7 >> 8);
    }
    for (; j < e; ++j) {
        int sr = csr_src[j];
        unsigned int w = un8[(size_t)sr * 64 + t];
        ax += fp8dec(w & 0xffu);
        ay += fp8dec(w >> 8);
    }
    ax += bx; ay += by;
    float inv = inv_deg[node];
    unsigned int vs = us[(size_t)node * 64 + t];
    float2 bb = ((const float2*)b0)[t];
    float h0 = fmaxf(bf2f((unsigned short)(vs & 0xffffu)) + ax * inv + bb.x, 0.0f);
    float h1 = fmaxf(bf2f((unsigned short)(vs >> 16)) + ay * inv + bb.y, 0.0f);
    hu[(size_t)node * 64 + t] = (unsigned)f2bf(h0) | ((unsigned)f2bf(h1) << 16);
}

// out[node][c] = t_self[node][c] + b1[c] + mean(t_neigh[src][c]); t_* bf16 [N][48].
// 4 waves/block, two 32-lane groups on alternating edges, x8 unroll per group.
__global__ __launch_bounds__(256) void final_out_kernel(const unsigned int* __restrict__ ts,
                                                        const unsigned int* __restrict__ tn,
                                                        const int* __restrict__ row_ptr,
                                                        const int* __restrict__ csr_src,
                                                        const float* __restrict__ inv_deg,
                                                        const float* __restrict__ b1,
                                                        float* __restrict__ out) {
    int node = blockIdx.x * 4 + (threadIdx.x >> 6);
    int lane = threadIdx.x & 63;
    int group = lane >> 5;
    int c = lane & 31;           // active c<24 (stray loads land in pad)
    int s = row_ptr[node], e = row_ptr[node + 1];
    float ax = 0.f, ay = 0.f, bx = 0.f, by = 0.f;
    int j = s + group;
    for (; j + 14 < e; j += 16) {
        int sr0 = csr_src[j],      sr1 = csr_src[j + 2];
        int sr2 = csr_src[j + 4],  sr3 = csr_src[j + 6];
        int sr4 = csr_src[j + 8],  sr5 = csr_src[j + 10];
        int sr6 = csr_src[j + 12], sr7 = csr_src[j + 14];
        unsigned int v0 = tn[(size_t)sr0 * 24 + c];
        unsigned int v1 = tn[(size_t)sr1 * 24 + c];
        unsigned int v2 = tn[(size_t)sr2 * 24 + c];
        unsigned int v3 = tn[(size_t)sr3 * 24 + c];
        unsigned int v4 = tn[(size_t)sr4 * 24 + c];
        unsigned int v5 = tn[(size_t)sr5 * 24 + c];
        unsigned int v6 = tn[(size_t)sr6 * 24 + c];
        unsigned int v7 = tn[(size_t)sr7 * 24 + c];
        ax += bf2f((unsigned short)(v0 & 0xffffu)) + bf2f((unsigned short)(v1 & 0xffffu));
        ay += bf2f((unsigned short)(v0 >> 16)) + bf2f((unsigned short)(v1 >> 16));
        bx += bf2f((unsigned short)(v2 & 0xffffu)) + bf2f((unsigned short)(v3 & 0xffffu));
        by += bf2f((unsigned short)(v2 >> 16)) + bf2f((unsigned short)(v3 >> 16));
        ax += bf2f((unsigned short)(v4 & 0xffffu)) + bf2f((unsigned short)(v5 & 0xffffu));
        ay += bf2f((unsigned short)(v4 >> 16)) + bf2f((unsigned short)(v5 >> 16));
        bx += bf2f((unsigned short)(v6 & 0xffffu)) + bf2f((unsigned short)(v7 & 0xffffu));
        by += bf2f((unsigned short)(v6 >> 16)) + bf2f((unsigned short)(v7 >> 16));
    }
    for (; j < e; j += 2) {
        int sr = csr_src[j];
        unsigned int v = tn[(size_t)sr * 24 + c];
        ax += bf2f((unsigned short)(v & 0xffffu));
        ay += bf2f((unsigned short)(v >> 16));
    }
    ax += bx; ay += by;
    ax += __shfl(ax, lane + 32, 64);
    ay += __shfl(ay, lane + 32, 64);
    if (lane >= 24) return;
    float inv = inv_deg[node];
    unsigned int vs = ts[(size_t)node * 24 + c];
    int c0 = 2 * c, c1 = 2 * c + 1;
    if (c0 < NC)
        out[(size_t)node * NC + c0] = bf2f((unsigned short)(vs & 0xffffu)) + b1[c0] + ax * inv;
    if (c1 < NC)
        out[(size_t)node * NC + c1] = bf2f((unsigned short)(vs >> 16)) + b1[c1] + ay * inv;
}

extern "C" void kernel_launch(void* const* d_in, const int* in_sizes, int n_in,
                              void* d_out, int out_size, void* d_ws, size_t ws_size,
                              hipStream_t stream) {
    const float* x   = (const float*)d_in[0];
    const int*   src = (const int*)d_in[1];
    const int*   dst = (const int*)d_in[2];
    const float* Ws0 = (const float*)d_in[3];
    const float* Wn0 = (const float*)d_in[4];
    const float* b0  = (const float*)d_in[5];
    const float* Ws1 = (const float*)d_in[6];
    const float* Wn1 = (const float*)d_in[7];
    const float* b1  = (const float*)d_in[8];
    float* out = (float*)d_out;

    char* ws = (char*)d_ws;
    size_t o = 0;
    auto alloc = [&](size_t bytes) {
        size_t r = o;
        o = (o + bytes + 255) & ~(size_t)255;
        return r;
    };
    int*   deg     = (int*)(ws + alloc(sizeof(int) * N_NODES));
    int*   local   = (int*)(ws + alloc(sizeof(int) * N_NODES));
    int*   bsum    = (int*)(ws + alloc(sizeof(int) * N_SCAN_BLKS));
    int*   row_ptr = (int*)(ws + alloc(sizeof(int) * (N_NODES + 1)));
    int*   cursor  = (int*)(ws + alloc(sizeof(int) * N_NODES));
    int*   csr     = (int*)(ws + alloc(sizeof(int) * N_EDGES));
    float* inv_deg = (float*)(ws + alloc(sizeof(float) * N_NODES));
    unsigned short* Bpk0 = (unsigned short*)(ws + alloc(sizeof(short) * 128 * 256));
    unsigned short* Bpk1 = (unsigned short*)(ws + alloc(sizeof(short) * 128 * 128));
    unsigned short* u_self = (unsigned short*)(ws + alloc(sizeof(short) * (size_t)N_NODES * 128));
    unsigned char*  u_nb8  = (unsigned char*)(ws + alloc((size_t)N_NODES * 128));
    unsigned short* h    = (unsigned short*)(ws + alloc(sizeof(short) * (size_t)N_NODES * 128));
    unsigned short* t_self  = (unsigned short*)(ws + alloc(sizeof(short) * (size_t)N_NODES * 48));
    unsigned short* t_neigh = (unsigned short*)(ws + alloc(sizeof(short) * ((size_t)N_NODES * 48 + 128)));  // +pad for stray lane reads

    hipMemsetAsync(deg, 0, sizeof(int) * N_NODES, stream);
    count_pack_kernel<<<COUNT_BLKS + PACK_BLKS, 256, 0, stream>>>(dst, deg, Ws0, Wn0, Ws1, Wn1,
                                                                  Bpk0, Bpk1);
    scan1_kernel<<<N_SCAN_BLKS, SCAN_BLK, 0, stream>>>(deg, local, bsum);
    scan2_kernel<<<1, SCAN_BLK, 0, stream>>>(bsum, row_ptr);
    scan3_kernel<<<N_SCAN_BLKS, SCAN_BLK, 0, stream>>>(deg, local, bsum, row_ptr, cursor, inv_deg);
    // fused: CSR fill (2048 blks) + GEMM A (782 blks) — independent, co-scheduled
    fill_gemmA_kernel<<<FILL_BLKS + GEMM_BLKS, 256, 0, stream>>>(src, dst, cursor, csr,
                                                                 x, Bpk0, u_self, u_nb8);
    // agg0: h = relu(u_self + mean(u_neigh fp8) + b0) -> bf16 [N][128]
    agg0_kernel<<<N_NODES / 4, 256, 0, stream>>>((const unsigned int*)u_self,
                                                 (const unsigned short*)u_nb8,
                                                 row_ptr, csr, inv_deg, b0, (unsigned int*)h);
    // GEMM B: t = h @ Wcat1 -> t_self bf16[N][48], t_neigh bf16[N][48]
    gemmB_kernel<<<GEMM_BLKS, 256, 0, stream>>>(h, Bpk1, t_self, t_neigh);
    // final: out = t_self + b1 + mean(t_neigh)
    final_out_kernel<<<N_NODES / 4, 256, 0, stream>>>((const unsigned int*)t_self,
                                                      (const unsigned int*)t_neigh,
                                                      row_ptr, csr, inv_deg, b1, out);
}